// Round 2
// baseline (128.125 us; speedup 1.0000x reference)
//
#include <hip/hip_runtime.h>
#include <math.h>

// NonLinearReadoutBlock, round 2: weights-in-registers + shuffle reduction.
// Per row: h_s[32] = x_s@W1s*inv1+b1, h_v[16][3] = x_v@W1v*inv1,
//          s=silu(h_s[:16]), g=silu(h_s[16:]),
//          out[:10] = s@W2s*0.25+b2, out[10:13] = (g[:,None]*h_v)@W2v*0.25.
// Wave layout: lane = (ig,og), ig=lane>>3 owns i in [16ig,16ig+16),
// og=lane&7 owns scalar outs [4og,4og+4) and vec outs [2og,2og+2).
// 96 weights/lane live in VGPRs; x comes from LDS (16 b128/row, 8-way bcast);
// 80 partials reduced via 3-step splitting butterfly (shfl_xor 8/16/32).

#define TILE 8      // rows per block-tile (8*512*4B = 16 KB LDS)
#define BLOCK 256
#define NW 4        // waves/block
#define RPW 2       // rows per wave per tile

__global__ __launch_bounds__(BLOCK, 2) void nlrb_kernel(
    const float* __restrict__ x,
    const float* __restrict__ W1s,   // (128,32)
    const float* __restrict__ W1v,   // (128,16)
    const float* __restrict__ b1s,   // (32)
    const float* __restrict__ W2s,   // (16,10)
    const float* __restrict__ W2v,   // (16)
    const float* __restrict__ b2s,   // (10)
    float* __restrict__ out,         // (N,13)
    int N)
{
    __shared__ __align__(16) float xs[TILE][512];   // 16 KB
    __shared__ __align__(16) float S [NW][8][16];   // reduce scratch, 2 KB
    __shared__ __align__(16) float S2[NW][4][16];   // finalize scratch, 1 KB

    const int tid  = threadIdx.x;
    const int wave = tid >> 6;
    const int lane = tid & 63;
    const int ig   = lane >> 3;
    const int og   = lane & 7;
    const int i0   = ig * 16;
    const float inv1 = 0.08838834764831843f;  // 1/sqrt(128)

    // ---- one-time: per-lane weights into registers ----
    float w1s[16][4], w1v[16][2];
    #pragma unroll
    for (int di = 0; di < 16; ++di) {
        float4 a = *(const float4*)(W1s + (i0 + di) * 32 + og * 4);
        w1s[di][0] = a.x; w1s[di][1] = a.y; w1s[di][2] = a.z; w1s[di][3] = a.w;
        float2 b = *(const float2*)(W1v + (i0 + di) * 16 + og * 2);
        w1v[di][0] = b.x; w1v[di][1] = b.y;
    }
    const int es = (lane < 10) ? lane : 0;   // safe W2s/b2s column index
    float wc[16];
    #pragma unroll
    for (int j = 0; j < 16; ++j)
        wc[j] = (lane < 10) ? W2s[j * 10 + es] : W2v[j];
    const float b2e = (lane < 10) ? b2s[es] : 0.0f;
    const int jf = lane & 15;
    const float b1a = b1s[jf];
    const float b1b = b1s[16 + jf];

    const int ntiles = N / TILE;   // 12500 exact
    int t = blockIdx.x;

    // ---- prologue: prefetch tile t into registers ----
    float4 R0, R1, R2, R3;
    {
        const float* src = x + (size_t)t * (TILE * 512) + wave * (RPW * 512) + lane * 4;
        R0 = *(const float4*)(src);
        R1 = *(const float4*)(src + 256);
        R2 = *(const float4*)(src + 512);
        R3 = *(const float4*)(src + 768);
    }

    for (; t < ntiles; t += gridDim.x) {
        // ---- write staged regs -> LDS (compiler inserts vmcnt waits) ----
        float* dst = &xs[wave * RPW][0] + lane * 4;
        *(float4*)(dst      ) = R0;
        *(float4*)(dst + 256) = R1;
        *(float4*)(dst + 512) = R2;
        *(float4*)(dst + 768) = R3;

        // ---- issue next tile's global loads (hide under compute) ----
        const int nxt = t + gridDim.x;
        if (nxt < ntiles) {
            const float* src = x + (size_t)nxt * (TILE * 512) + wave * (RPW * 512) + lane * 4;
            R0 = *(const float4*)(src);
            R1 = *(const float4*)(src + 256);
            R2 = *(const float4*)(src + 512);
            R3 = *(const float4*)(src + 768);
        }

        asm volatile("s_waitcnt lgkmcnt(0)" ::: "memory");
        __builtin_amdgcn_s_barrier();
        __builtin_amdgcn_sched_barrier(0);

        #pragma unroll
        for (int r = 0; r < RPW; ++r) {
            const float* xr = &xs[wave * RPW + r][0];

            // ---- layer 1: 160 FMA/lane-row, weights from regs ----
            float as0 = 0.f, as1 = 0.f, as2 = 0.f, as3 = 0.f;
            float av[2][3] = {{0.f,0.f,0.f},{0.f,0.f,0.f}};
            #pragma unroll
            for (int q = 0; q < 4; ++q) {
                float4 xa = *(const float4*)(xr + i0 + q * 4);
                const float xe[4] = {xa.x, xa.y, xa.z, xa.w};
                #pragma unroll
                for (int d = 0; d < 4; ++d) {
                    const int di = q * 4 + d;
                    as0 = fmaf(xe[d], w1s[di][0], as0);
                    as1 = fmaf(xe[d], w1s[di][1], as1);
                    as2 = fmaf(xe[d], w1s[di][2], as2);
                    as3 = fmaf(xe[d], w1s[di][3], as3);
                }
            }
            #pragma unroll
            for (int m = 0; m < 12; ++m) {
                float4 xa = *(const float4*)(xr + 128 + ig * 48 + m * 4);
                const float xe[4] = {xa.x, xa.y, xa.z, xa.w};
                #pragma unroll
                for (int jj = 0; jj < 4; ++jj) {
                    const int eidx = m * 4 + jj;        // 0..47
                    const int di = eidx / 3, c = eidx % 3;
                    av[0][c] = fmaf(xe[jj], w1v[di][0], av[0][c]);
                    av[1][c] = fmaf(xe[jj], w1v[di][1], av[1][c]);
                }
            }

            // ---- splitting butterfly over ig (masks 8,16,32) ----
            // value space per og: k 0..3 = h_s chunk, 4..9 = h_v[o2][c], 10..15 = 0
            const bool b3 = (lane & 8)  != 0;
            float s0 = (b3 ? av[1][1] : as0) + __shfl_xor(b3 ? as0 : av[1][1], 8, 64); // k 0 / 8
            float s1 = (b3 ? av[1][2] : as1) + __shfl_xor(b3 ? as1 : av[1][2], 8, 64); // k 1 / 9
            float s2 = (b3 ? 0.f      : as2) + __shfl_xor(b3 ? as2 : 0.f,      8, 64); // k 2 / 10
            float s3 = (b3 ? 0.f      : as3) + __shfl_xor(b3 ? as3 : 0.f,      8, 64); // k 3 / 11
            float s4 = (b3 ? 0.f : av[0][0]) + __shfl_xor(b3 ? av[0][0] : 0.f, 8, 64); // k 4 / 12
            float s5 = (b3 ? 0.f : av[0][1]) + __shfl_xor(b3 ? av[0][1] : 0.f, 8, 64); // k 5 / 13
            float s6 = (b3 ? 0.f : av[0][2]) + __shfl_xor(b3 ? av[0][2] : 0.f, 8, 64); // k 6 / 14
            float s7 = (b3 ? 0.f : av[1][0]) + __shfl_xor(b3 ? av[1][0] : 0.f, 8, 64); // k 7 / 15
            const bool b4 = (lane & 16) != 0;
            float u0 = (b4 ? s4 : s0) + __shfl_xor(b4 ? s0 : s4, 16, 64);
            float u1 = (b4 ? s5 : s1) + __shfl_xor(b4 ? s1 : s5, 16, 64);
            float u2 = (b4 ? s6 : s2) + __shfl_xor(b4 ? s2 : s6, 16, 64);
            float u3 = (b4 ? s7 : s3) + __shfl_xor(b4 ? s3 : s7, 16, 64);
            const bool b5 = (lane & 32) != 0;
            float z0 = (b5 ? u2 : u0) + __shfl_xor(b5 ? u0 : u2, 32, 64);
            float z1 = (b5 ? u3 : u1) + __shfl_xor(b5 ? u1 : u3, 32, 64);
            const int k0i = ((lane >> 3) & 1) * 8 + ((lane >> 4) & 1) * 4
                          + ((lane >> 5) & 1) * 2;
            *(float2*)&S[wave][og][k0i] = make_float2(z0, z1);

            asm volatile("s_waitcnt lgkmcnt(0)" ::: "memory");

            // ---- finalize: silu + gating (lanes 0..15, wave-private) ----
            if (lane < 16) {
                const int j = lane;
                float hs = S[wave][j >> 2][j & 3]       * inv1 + b1a;
                float hg = S[wave][4 + (j >> 2)][j & 3] * inv1 + b1b;
                float sj = hs / (1.f + __expf(-hs));
                float gj = hg / (1.f + __expf(-hg));
                float gm = gj * inv1;
                float hv0 = S[wave][j >> 1][4 + (j & 1) * 3 + 0];
                float hv1 = S[wave][j >> 1][4 + (j & 1) * 3 + 1];
                float hv2 = S[wave][j >> 1][4 + (j & 1) * 3 + 2];
                S2[wave][0][j] = sj;
                S2[wave][1][j] = gm * hv0;
                S2[wave][2][j] = gm * hv1;
                S2[wave][3][j] = gm * hv2;
            }
            asm volatile("s_waitcnt lgkmcnt(0)" ::: "memory");

            // ---- layer 2: 13 lanes, dot-16 from regs ----
            if (lane < 13) {
                const int slot = (lane < 10) ? 0 : (lane - 9);
                const float* s2p = &S2[wave][slot][0];
                float sum = 0.f;
                #pragma unroll
                for (int j2 = 0; j2 < 16; ++j2)
                    sum = fmaf(s2p[j2], wc[j2], sum);
                const int rowg = t * TILE + wave * RPW + r;
                out[(size_t)rowg * 13 + lane] = fmaf(sum, 0.25f, b2e);
            }
        }

        asm volatile("s_waitcnt lgkmcnt(0)" ::: "memory");
        __builtin_amdgcn_s_barrier();    // xs safe to overwrite next iter
        __builtin_amdgcn_sched_barrier(0);
    }
}

extern "C" void kernel_launch(void* const* d_in, const int* in_sizes, int n_in,
                              void* d_out, int out_size, void* d_ws, size_t ws_size,
                              hipStream_t stream) {
    const float* x   = (const float*)d_in[0];
    const float* W1s = (const float*)d_in[1];
    const float* W1v = (const float*)d_in[2];
    const float* b1s = (const float*)d_in[3];
    const float* W2s = (const float*)d_in[4];
    const float* W2v = (const float*)d_in[5];
    const float* b2s = (const float*)d_in[6];
    float* outp = (float*)d_out;
    const int N = in_sizes[0] / 512;   // 100000
    nlrb_kernel<<<dim3(1024), dim3(BLOCK), 0, stream>>>(
        x, W1s, W1v, b1s, W2s, W2v, b2s, outp, N);
}

// Round 3
// 41.802 us; speedup vs baseline: 3.0651x; 3.0651x over previous
//
#include <hip/hip_runtime.h>
#include <math.h>

// NonLinearReadoutBlock, round 3: bf16 MFMA layer-1, weights resident in VGPRs,
// A-fragments built straight from per-lane global loads (no x LDS, no barriers).
//
// Per 16-row tile per wave (lane = (mq=l>>4, o=l&15)):
//   A_s[kb]  : x[row=o][k = kb*32 + mq*8 + j]            (8 consecutive floats)
//   A_vc[kb] : x[row=o][128 + 3*(kb*32+mq*8+j) + c]      (stride-3 pick of 24)
//   B_s[nt][kb][j] = W1s[kb*32+mq*8+j][nt*16+o]          (resident, bf16x8)
//   B_v[kb][j]     = W1v[kb*32+mq*8+j][o]                (resident, bf16x8)
//   accS0/accS1 (h_s), accV0..2 (h_v per c) : f32x4, C-layout col=o, row=mq*4+v
// Epilogue lane-local: hs,hg -> silu; gated = g*hv*inv1. Layer 2 via tiny
// wave-private LDS (sred) + per-lane fp32 weights wcr[16]. 100000 = 6250*16.

typedef short  bf16x8 __attribute__((ext_vector_type(8)));
typedef float  f32x4  __attribute__((ext_vector_type(4)));

static __device__ __forceinline__ short f2bf(float f) {
    union { float f; unsigned u; } v; v.f = f;
    return (short)((v.u + 0x8000u) >> 16);   // round-half-up on magnitude
}

#define BLOCK 256

__global__ __launch_bounds__(BLOCK, 2) void nlrb_kernel(
    const float* __restrict__ x,
    const float* __restrict__ W1s,   // (128,32)
    const float* __restrict__ W1v,   // (128,16)
    const float* __restrict__ b1s,   // (32)
    const float* __restrict__ W2s,   // (16,10)
    const float* __restrict__ W2v,   // (16)
    const float* __restrict__ b2s,   // (10)
    float* __restrict__ out,         // (N,13)
    int N)
{
    __shared__ float sred[4][16][68];   // [wave][row][slot*16+o], pad->68

    const int tid  = threadIdx.x;
    const int wave = tid >> 6;
    const int lane = tid & 63;
    const int mq   = lane >> 4;   // k-chunk group
    const int o    = lane & 15;   // output col / row-within-tile for A loads
    const float inv1 = 0.08838834764831843f;  // 1/sqrt(128)

    // ---- one-time: resident B fragments (bf16) ----
    bf16x8 bS0[4], bS1[4], bV[4];
    #pragma unroll
    for (int kb = 0; kb < 4; ++kb) {
        #pragma unroll
        for (int j = 0; j < 8; ++j) {
            const int k = kb * 32 + mq * 8 + j;
            bS0[kb][j] = f2bf(W1s[k * 32 + o]);
            bS1[kb][j] = f2bf(W1s[k * 32 + 16 + o]);
            bV [kb][j] = f2bf(W1v[k * 16 + o]);
        }
    }
    // ---- one-time: layer-2 weights (fp32, per-lane) ----
    const int e = o;                       // output element this lane owns
    float wcr[16];
    #pragma unroll
    for (int j = 0; j < 16; ++j)
        wcr[j] = (e < 10) ? W2s[j * 10 + e] : W2v[j];
    const float b2e = (e < 10) ? b2s[e] : 0.0f;
    const float b1a = b1s[o];
    const float b1b = b1s[16 + o];

    const int NT = N >> 4;                 // 6250 full 16-row tiles
    const int wstride = gridDim.x << 2;

    for (int wt = (blockIdx.x << 2) + wave; wt < NT; wt += wstride) {
        const int base = wt << 4;
        const float* xp = x + (size_t)(base + o) * 512;

        // ---- issue all global loads for this tile (2048B/row, no LDS) ----
        float4 LS[4][2], LV[4][6];
        #pragma unroll
        for (int kb = 0; kb < 4; ++kb) {
            LS[kb][0] = *(const float4*)(xp + kb * 32 + mq * 8);
            LS[kb][1] = *(const float4*)(xp + kb * 32 + mq * 8 + 4);
        }
        #pragma unroll
        for (int kb = 0; kb < 4; ++kb) {
            #pragma unroll
            for (int q = 0; q < 6; ++q)
                LV[kb][q] = *(const float4*)(xp + 128 + kb * 96 + mq * 24 + q * 4);
        }

        f32x4 accS0 = {0.f,0.f,0.f,0.f}, accS1 = {0.f,0.f,0.f,0.f};
        f32x4 accV0 = {0.f,0.f,0.f,0.f}, accV1 = {0.f,0.f,0.f,0.f};
        f32x4 accV2 = {0.f,0.f,0.f,0.f};

        // ---- h_s GEMM: 2 n-tiles x 4 k-blocks ----
        #pragma unroll
        for (int kb = 0; kb < 4; ++kb) {
            float u[8];
            u[0]=LS[kb][0].x; u[1]=LS[kb][0].y; u[2]=LS[kb][0].z; u[3]=LS[kb][0].w;
            u[4]=LS[kb][1].x; u[5]=LS[kb][1].y; u[6]=LS[kb][1].z; u[7]=LS[kb][1].w;
            bf16x8 a;
            #pragma unroll
            for (int j = 0; j < 8; ++j) a[j] = f2bf(u[j]);
            accS0 = __builtin_amdgcn_mfma_f32_16x16x32_bf16(a, bS0[kb], accS0, 0, 0, 0);
            accS1 = __builtin_amdgcn_mfma_f32_16x16x32_bf16(a, bS1[kb], accS1, 0, 0, 0);
        }
        // ---- h_v GEMMs: 3 c-matrices share one B ----
        #pragma unroll
        for (int kb = 0; kb < 4; ++kb) {
            float t[24];
            #pragma unroll
            for (int q = 0; q < 6; ++q) {
                t[4*q+0] = LV[kb][q].x; t[4*q+1] = LV[kb][q].y;
                t[4*q+2] = LV[kb][q].z; t[4*q+3] = LV[kb][q].w;
            }
            bf16x8 a0, a1, a2;
            #pragma unroll
            for (int j = 0; j < 8; ++j) {
                a0[j] = f2bf(t[3*j+0]);
                a1[j] = f2bf(t[3*j+1]);
                a2[j] = f2bf(t[3*j+2]);
            }
            accV0 = __builtin_amdgcn_mfma_f32_16x16x32_bf16(a0, bV[kb], accV0, 0, 0, 0);
            accV1 = __builtin_amdgcn_mfma_f32_16x16x32_bf16(a1, bV[kb], accV1, 0, 0, 0);
            accV2 = __builtin_amdgcn_mfma_f32_16x16x32_bf16(a2, bV[kb], accV2, 0, 0, 0);
        }

        // ---- epilogue: lane-local silu + gating; write layer-2 operands ----
        #pragma unroll
        for (int v = 0; v < 4; ++v) {
            const float hs = fmaf(accS0[v], inv1, b1a);
            const float hg = fmaf(accS1[v], inv1, b1b);
            const float s  = hs / (1.f + __expf(-hs));
            const float g  = hg / (1.f + __expf(-hg));
            const float gm = g * inv1;
            const int  r   = mq * 4 + v;
            sred[wave][r][o]      = s;
            sred[wave][r][16 + o] = gm * accV0[v];
            sred[wave][r][32 + o] = gm * accV1[v];
            sred[wave][r][48 + o] = gm * accV2[v];
        }
        asm volatile("s_waitcnt lgkmcnt(0)" ::: "memory");

        // ---- layer 2: lane (e<13) does dot-16 for rows mq, mq+4, mq+8, mq+12
        #pragma unroll
        for (int w = 0; w < 4; ++w) {
            const int r = (w << 2) + mq;
            if (e < 13) {
                const int slot = (e < 10) ? 0 : (e - 9);
                const float* p = &sred[wave][r][slot * 16];
                float sum = 0.f;
                #pragma unroll
                for (int j = 0; j < 16; ++j)
                    sum = fmaf(p[j], wcr[j], sum);
                out[(size_t)(base + r) * 13 + e] = fmaf(sum, 0.25f, b2e);
            }
        }
        asm volatile("s_waitcnt lgkmcnt(0)" ::: "memory");  // reads done before
                                                            // next tile's writes
    }
}

extern "C" void kernel_launch(void* const* d_in, const int* in_sizes, int n_in,
                              void* d_out, int out_size, void* d_ws, size_t ws_size,
                              hipStream_t stream) {
    const float* x   = (const float*)d_in[0];
    const float* W1s = (const float*)d_in[1];
    const float* W1v = (const float*)d_in[2];
    const float* b1s = (const float*)d_in[3];
    const float* W2s = (const float*)d_in[4];
    const float* W2v = (const float*)d_in[5];
    const float* b2s = (const float*)d_in[6];
    float* outp = (float*)d_out;
    const int N = in_sizes[0] / 512;   // 100000
    nlrb_kernel<<<dim3(512), dim3(BLOCK), 0, stream>>>(
        x, W1s, W1v, b1s, W2s, W2v, b2s, outp, N);
}